// Round 9
// baseline (44.680 us; speedup 1.0000x reference)
//
#include <hip/hip_runtime.h>

// QuantizationLoss: sum over all elements of min(1, min_i |x - (i/127.5 - 1)|),
// i in [0,255]. Scan init = ones_like caps the distance at 1.0.
// Closed form: nearest level of the uniform grid on [-1,1], step 1/127.5:
//   r = clamp(rint((x+1)*127.5), 0, 255);  dist = min(1, |x - (r/127.5 - 1)|)
//
// Round 8 -> 9: single-kernel last-block finish WITHOUT __threadfence.
// r7's 127 us came from 2048 device-scope fences (XCD-L2 writeback each).
// Here: partials are agent-scope relaxed ATOMIC stores (reach the coherence
// point, no cache flush), ordered before the ticket atomicAdd by a plain
// s_waitcnt vmcnt(0) (drains only this wave's stores). Ticket zeroed by a
// 4-byte memsetAsync BEFORE the kernel (pre-stream, off the critical tail).
// NT loads kept from r6 (best: 26.1 us).

#define BLOCK  512
#define UNROLL 8

typedef float vfloat4 __attribute__((ext_vector_type(4)));

__device__ __forceinline__ float qdist(float x) {
    const float INV_D = 127.5f;
    const float D     = 1.0f / 127.5f;
    float r = rintf(__builtin_fmaf(x, INV_D, INV_D)); // (x+1)*127.5
    r = fminf(fmaxf(r, 0.0f), 255.0f);                // v_med3
    float lv = __builtin_fmaf(r, D, -1.0f);
    return fminf(fabsf(x - lv), 1.0f);                // scan init = 1 caps min
}

__device__ __forceinline__ float qdist4(vfloat4 v) {
    return (qdist(v.x) + qdist(v.y)) + (qdist(v.z) + qdist(v.w));
}

__global__ __launch_bounds__(BLOCK) void ql_kernel(
    const vfloat4* __restrict__ in4, int n4,
    const float* __restrict__ in_tail, int ntail,
    float* __restrict__ partial,          // d_ws + 256
    unsigned* __restrict__ ticket,        // d_ws + 0 (zeroed by memsetAsync)
    float* __restrict__ out)
{
    const int CH = gridDim.x * (BLOCK * UNROLL);     // float4s per grid pass

    float a[UNROLL];
    #pragma unroll
    for (int u = 0; u < UNROLL; ++u) a[u] = 0.0f;

    // grid normally covers n4 in one pass; loop only repeats if clamped.
    for (int base = blockIdx.x * (BLOCK * UNROLL) + threadIdx.x;
         base < n4; base += CH) {
        if (base + (UNROLL - 1) * BLOCK < n4) {       // fast path
            vfloat4 v[UNROLL];
            #pragma unroll
            for (int u = 0; u < UNROLL; ++u)
                v[u] = __builtin_nontemporal_load(&in4[base + u * BLOCK]);
            #pragma unroll
            for (int u = 0; u < UNROLL; ++u) a[u] += qdist4(v[u]);
        } else {                                       // edge block
            #pragma unroll
            for (int u = 0; u < UNROLL; ++u) {
                int i = base + u * BLOCK;
                if (i < n4) a[u] += qdist4(__builtin_nontemporal_load(&in4[i]));
            }
        }
    }

    // scalar tail (n not divisible by 4), first ntail threads of block 0
    if (blockIdx.x == 0 && threadIdx.x < ntail) a[0] += qdist(in_tail[threadIdx.x]);

    float acc = 0.0f;
    #pragma unroll
    for (int u = 0; u < UNROLL; ++u) acc += a[u];

    #pragma unroll
    for (int off = 32; off > 0; off >>= 1)
        acc += __shfl_down(acc, off, 64);

    __shared__ float smem[BLOCK / 64];
    __shared__ unsigned is_last;
    int lane = threadIdx.x & 63;
    int wid  = threadIdx.x >> 6;
    if (lane == 0) smem[wid] = acc;
    __syncthreads();

    if (threadIdx.x == 0) {
        float s = 0.0f;
        #pragma unroll
        for (int w = 0; w < BLOCK / 64; ++w) s += smem[w];
        // agent-scope atomic store: bypasses non-coherent XCD L2, lands at
        // the coherence point. NO threadfence (that was r7's 5x regression).
        __hip_atomic_store(&partial[blockIdx.x], s, __ATOMIC_RELAXED,
                           __HIP_MEMORY_SCOPE_AGENT);
        // drain THIS wave's stores only, then take a ticket
        asm volatile("s_waitcnt vmcnt(0)" ::: "memory");
        unsigned prev = __hip_atomic_fetch_add(ticket, 1u, __ATOMIC_RELAXED,
                                               __HIP_MEMORY_SCOPE_AGENT);
        is_last = (prev == gridDim.x - 1) ? 1u : 0u;
    }
    __syncthreads();

    if (is_last) {                                     // last block: final sum
        float facc = 0.0f;
        for (int i = threadIdx.x; i < (int)gridDim.x; i += BLOCK)
            facc += __hip_atomic_load(&partial[i], __ATOMIC_RELAXED,
                                      __HIP_MEMORY_SCOPE_AGENT);
        #pragma unroll
        for (int off = 32; off > 0; off >>= 1)
            facc += __shfl_down(facc, off, 64);
        if (lane == 0) smem[wid] = facc;
        __syncthreads();
        if (threadIdx.x == 0) {
            float s = 0.0f;
            #pragma unroll
            for (int w = 0; w < BLOCK / 64; ++w) s += smem[w];
            out[0] = s;                                // overwrites poison
        }
    }
}

extern "C" void kernel_launch(void* const* d_in, const int* in_sizes, int n_in,
                              void* d_out, int out_size, void* d_ws, size_t ws_size,
                              hipStream_t stream) {
    const float* x = (const float*)d_in[0];
    float* out       = (float*)d_out;
    unsigned* ticket = (unsigned*)d_ws;                // 4 B at offset 0
    float* partial   = (float*)((char*)d_ws + 256);    // partials after pad
    int n = in_sizes[0];

    int n4    = n >> 2;
    int ntail = n & 3;
    const float* tail = x + (n4 << 2);

    int grid = (n4 + BLOCK * UNROLL - 1) / (BLOCK * UNROLL);   // 2048 for n4=8M
    int maxp = (int)((ws_size - 256) / sizeof(float));
    if (grid > maxp) grid = maxp;        // safety: partials must fit d_ws
    if (grid < 1) grid = 1;

    hipMemsetAsync(ticket, 0, sizeof(unsigned), stream);   // zero the ticket

    ql_kernel<<<grid, BLOCK, 0, stream>>>(
        (const vfloat4*)x, n4, tail, ntail, partial, ticket, out);
}

// Round 10
// 24.404 us; speedup vs baseline: 1.8308x; 1.8308x over previous
//
#include <hip/hip_runtime.h>

// QuantizationLoss: sum over all elements of min(1, min_i |x - (i/127.5 - 1)|),
// i in [0,255]. Scan init = ones_like caps the distance at 1.0.
// Closed form: nearest level of the uniform grid on [-1,1], step 1/127.5:
//   r = clamp(rint((x+1)*127.5), 0, 255);  dist = min(1, |x - (r/127.5 - 1)|)
//
// Round 9 -> 10: back to the proven r6 two-kernel structure (26.1 us).
// Ladder lesson: any hipMemsetAsync dispatch inside the timed graph costs
// ~15 us serialized (r3->r4, r9), so counter-based single-kernel finishes
// lose; the 2nd kernel dispatch (~3 us) is the cheaper tail. This round:
// UNROLL 8 -> 16 (16 NT dwordx4 in flight per wave, 128 KB span per block,
// grid 1024) to push k1 from ~6.0 toward the 6.3 TB/s read ceiling.

#define BLOCK  512
#define UNROLL 16

typedef float vfloat4 __attribute__((ext_vector_type(4)));

__device__ __forceinline__ float qdist(float x) {
    const float INV_D = 127.5f;
    const float D     = 1.0f / 127.5f;
    float r = rintf(__builtin_fmaf(x, INV_D, INV_D)); // (x+1)*127.5
    r = fminf(fmaxf(r, 0.0f), 255.0f);                // v_med3
    float lv = __builtin_fmaf(r, D, -1.0f);
    return fminf(fabsf(x - lv), 1.0f);                // scan init = 1 caps min
}

__device__ __forceinline__ float qdist4(vfloat4 v) {
    return (qdist(v.x) + qdist(v.y)) + (qdist(v.z) + qdist(v.w));
}

__global__ __launch_bounds__(BLOCK) void ql_partial_kernel(
    const vfloat4* __restrict__ in4, int n4,
    const float* __restrict__ in_tail, int ntail,
    float* __restrict__ partial)
{
    // Block b owns [b*BLOCK*UNROLL, (b+1)*BLOCK*UNROLL) float4s; thread t
    // loads t + u*BLOCK (u = 0..15), all issued together (non-temporal).
    const int base = blockIdx.x * (BLOCK * UNROLL) + threadIdx.x;

    float a[UNROLL];
    #pragma unroll
    for (int u = 0; u < UNROLL; ++u) a[u] = 0.0f;

    if (base + (UNROLL - 1) * BLOCK < n4) {          // fast path: all in bounds
        vfloat4 v[UNROLL];
        #pragma unroll
        for (int u = 0; u < UNROLL; ++u)
            v[u] = __builtin_nontemporal_load(&in4[base + u * BLOCK]);
        #pragma unroll
        for (int u = 0; u < UNROLL; ++u) a[u] += qdist4(v[u]);
    } else {                                          // edge block
        #pragma unroll
        for (int u = 0; u < UNROLL; ++u) {
            int i = base + u * BLOCK;
            if (i < n4) a[u] += qdist4(__builtin_nontemporal_load(&in4[i]));
        }
    }

    // scalar tail (n not divisible by 4), first ntail threads of block 0
    if (blockIdx.x == 0 && threadIdx.x < ntail) a[0] += qdist(in_tail[threadIdx.x]);

    float acc = 0.0f;
    #pragma unroll
    for (int u = 0; u < UNROLL; ++u) acc += a[u];

    #pragma unroll
    for (int off = 32; off > 0; off >>= 1)
        acc += __shfl_down(acc, off, 64);

    __shared__ float smem[BLOCK / 64];
    int lane = threadIdx.x & 63;
    int wid  = threadIdx.x >> 6;
    if (lane == 0) smem[wid] = acc;
    __syncthreads();

    if (threadIdx.x == 0) {
        float s = 0.0f;
        #pragma unroll
        for (int w = 0; w < BLOCK / 64; ++w) s += smem[w];
        partial[blockIdx.x] = s;   // plain store, no atomics
    }
}

#define FBLOCK 1024
__global__ __launch_bounds__(FBLOCK) void ql_final_kernel(
    const float* __restrict__ partial, int np, float* __restrict__ out)
{
    float acc = 0.0f;
    // np is even (grid is a power-of-two-ish count); read as float2 pairs,
    // with a scalar guard for odd np.
    const float2* p2 = (const float2*)partial;
    int np2 = np >> 1;
    for (int i = threadIdx.x; i < np2; i += FBLOCK) {
        float2 v = p2[i];
        acc += v.x + v.y;
    }
    if ((np & 1) && threadIdx.x == 0) acc += partial[np - 1];

    #pragma unroll
    for (int off = 32; off > 0; off >>= 1)
        acc += __shfl_down(acc, off, 64);

    __shared__ float smem[FBLOCK / 64];
    int lane = threadIdx.x & 63;
    int wid  = threadIdx.x >> 6;
    if (lane == 0) smem[wid] = acc;
    __syncthreads();

    if (threadIdx.x == 0) {
        float s = 0.0f;
        #pragma unroll
        for (int w = 0; w < FBLOCK / 64; ++w) s += smem[w];
        out[0] = s;                // overwrites poison; no memset needed
    }
}

extern "C" void kernel_launch(void* const* d_in, const int* in_sizes, int n_in,
                              void* d_out, int out_size, void* d_ws, size_t ws_size,
                              hipStream_t stream) {
    const float* x = (const float*)d_in[0];
    float* out     = (float*)d_out;
    float* partial = (float*)d_ws;
    int n = in_sizes[0];

    int n4    = n >> 2;
    int ntail = n & 3;
    const float* tail = x + (n4 << 2);

    int grid = (n4 + BLOCK * UNROLL - 1) / (BLOCK * UNROLL);   // 1024 for n4=8M
    int maxp = (int)(ws_size / sizeof(float));
    if (grid > maxp) grid = maxp;        // safety: partials must fit d_ws
    if (grid < 1) grid = 1;

    ql_partial_kernel<<<grid, BLOCK, 0, stream>>>(
        (const vfloat4*)x, n4, tail, ntail, partial);
    ql_final_kernel<<<1, FBLOCK, 0, stream>>>(partial, grid, out);
}